// Round 8
// baseline (304.413 us; speedup 1.0000x reference)
//
#include <hip/hip_runtime.h>
#include <stdint.h>

#define BATCH 8
#define NCH 256
#define BCH 128
#define KFR 32000
#define TOUT 256008
#define KT 32
#define NTPB 5
#define CHUNK (KT * NTPB)        // 160 frames per block
#define NCHUNK (KFR / CHUNK)     // 200
#define ESTW 64                  // words per est row (32 rows)
#define XTW 128                  // words per xt row (32 rows)
#define LOC_FLOATS (8 * CHUNK + 8)   // 1288

typedef __attribute__((ext_vector_type(8))) short bf16x8;
typedef __attribute__((ext_vector_type(4))) float f32x4;

__device__ __forceinline__ unsigned short f32_to_bf16(float f) {
    unsigned int u = __builtin_bit_cast(unsigned int, f);
    u += 0x7FFFu + ((u >> 16) & 1u);
    return (unsigned short)(u >> 16);
}
__device__ __forceinline__ unsigned int pack2(float a, float b) {
    return (unsigned int)f32_to_bf16(a) | ((unsigned int)f32_to_bf16(b) << 16);
}
// 4 strided scalar loads (stride = KFR rows) into an ext_vector (SROA-safe)
__device__ __forceinline__ f32x4 mload(const float* p) {
    f32x4 v;
    v[0] = p[0];
    v[1] = p[(size_t)KFR];
    v[2] = p[(size_t)2 * KFR];
    v[3] = p[(size_t)3 * KFR];
    return v;
}
// 16B-granular XOR swizzle: row-local word offset w -> swizzled word offset.
__device__ __forceinline__ int swz(int row, int w) {
    return (((w >> 2) ^ (((row >> 2) & 3) << 1)) << 2) | (w & 3);
}

__global__ void convert_weights(const float* __restrict__ Wm,
                                const float* __restrict__ Wb,
                                unsigned short* __restrict__ wbf) {
    int i = blockIdx.x * 256 + threadIdx.x;
    if (i < NCH * BCH) wbf[i] = f32_to_bf16(Wm[i]);
    if (i < 16 * NCH)  wbf[NCH * BCH + i] = f32_to_bf16(Wb[i]);
}

// one GEMM1 16x16 tile (nt,ft) + fused relu*mix epilogue -> xt (swizzled)
#define G1(NT, FT, MM) { \
    const unsigned short* wr = wbf + (64 * wv + 16 * (NT) + l15) * BCH + 8 * lq; \
    bf16x8 w0 = *reinterpret_cast<const bf16x8*>(wr); \
    bf16x8 w1 = *reinterpret_cast<const bf16x8*>(wr + 32); \
    bf16x8 w2 = *reinterpret_cast<const bf16x8*>(wr + 64); \
    bf16x8 w3 = *reinterpret_cast<const bf16x8*>(wr + 96); \
    int f = 16 * (FT) + l15; \
    int sg = ((f >> 2) & 3) << 1; \
    const unsigned int* br = estd + f * ESTW; \
    f32x4 a = {0.f, 0.f, 0.f, 0.f}; \
    a = __builtin_amdgcn_mfma_f32_16x16x32_bf16(w0, *reinterpret_cast<const bf16x8*>(br + (((0  + lq) ^ sg) << 2)), a, 0, 0, 0); \
    a = __builtin_amdgcn_mfma_f32_16x16x32_bf16(w1, *reinterpret_cast<const bf16x8*>(br + (((4  + lq) ^ sg) << 2)), a, 0, 0, 0); \
    a = __builtin_amdgcn_mfma_f32_16x16x32_bf16(w2, *reinterpret_cast<const bf16x8*>(br + (((8  + lq) ^ sg) << 2)), a, 0, 0, 0); \
    a = __builtin_amdgcn_mfma_f32_16x16x32_bf16(w3, *reinterpret_cast<const bf16x8*>(br + (((12 + lq) ^ sg) << 2)), a, 0, 0, 0); \
    float x0 = (a[0] > 0.f) ? (MM)[0] * a[0] : 0.f; \
    float x1 = (a[1] > 0.f) ? (MM)[1] * a[1] : 0.f; \
    float x2 = (a[2] > 0.f) ? (MM)[2] * a[2] : 0.f; \
    float x3 = (a[3] > 0.f) ? (MM)[3] * a[3] : 0.f; \
    int ue = 8 * wv + 2 * (NT) + (lq >> 1); \
    uint2 uu; uu.x = pack2(x0, x1); uu.y = pack2(x2, x3); \
    *reinterpret_cast<uint2*>(xtd + f * XTW + (((ue ^ sg) << 2) | (2 * (lq & 1)))) = uu; \
}

__global__ __launch_bounds__(256, 5)
void fused_decoder(const float* __restrict__ mix,
                   const float* __restrict__ est,
                   const unsigned short* __restrict__ wbf,
                   float* __restrict__ out) {
    __shared__ __align__(16) unsigned int smem[32 * ESTW + 32 * XTW + LOC_FLOATS];
    unsigned int* estd = smem;
    unsigned int* xtd  = smem + 32 * ESTW;
    float* locout = reinterpret_cast<float*>(smem + 32 * ESTW + 32 * XTW);

    const int tid = threadIdx.x;
    const int lane = tid & 63;
    const int wv = tid >> 6;
    const int l15 = lane & 15;
    const int lq = lane >> 4;
    const int f4 = tid & 7;          // staging frame-quad
    const int c0 = tid >> 3;         // staging b-pair base, 0..31

    const int bid = blockIdx.x;
    const int g = bid / NCHUNK;
    const int c = bid % NCHUNK;

    const float* eg0 = est + ((size_t)g * BCH) * KFR + c * CHUNK;
    const float* mg0 = mix + ((size_t)g * NCH) * KFR + c * CHUNK;

    // zero the chunk accumulator (seam quads need 0 start; rest overwritten)
    for (int s = tid; s < LOC_FLOATS / 4; s += 256) {
        f32x4 z = {0.f, 0.f, 0.f, 0.f};
        *reinterpret_cast<f32x4*>(locout + 4 * s) = z;
    }

    // prologue: est[0] loads (16 regs)
    f32x4 er00, er01, er10, er11;
    {
        er00 = *reinterpret_cast<const f32x4*>(eg0 + (size_t)(2 * c0) * KFR + 4 * f4);
        er01 = *reinterpret_cast<const f32x4*>(eg0 + (size_t)(2 * c0 + 1) * KFR + 4 * f4);
        er10 = *reinterpret_cast<const f32x4*>(eg0 + (size_t)(2 * c0 + 64) * KFR + 4 * f4);
        er11 = *reinterpret_cast<const f32x4*>(eg0 + (size_t)(2 * c0 + 65) * KFR + 4 * f4);
    }

    for (int t = 0; t < NTPB; ++t) {
        const float* mg = mg0 + t * KT;

        // ---- phase A: est regs -> LDS estd (transposed bf16, swizzled) ----
#pragma unroll
        for (int i = 0; i < 4; ++i) {
            int row = 4 * f4 + i;
            estd[row * ESTW + swz(row, c0)]      = pack2(er00[i], er01[i]);
            estd[row * ESTW + swz(row, c0 + 32)] = pack2(er10[i], er11[i]);
        }
        __syncthreads();   // estd ready (also orders locout zero/reads)

        // ---- phase B: GEMM1 + fused relu*mix epilogue -> xt ----
        const float* pm = mg + (size_t)(64 * wv + 4 * lq) * KFR + l15;
        f32x4 ma0 = mload(pm);
        f32x4 ma1 = mload(pm + (size_t)16 * KFR);
        f32x4 ma2 = mload(pm + (size_t)32 * KFR);
        f32x4 ma3 = mload(pm + (size_t)48 * KFR);
        G1(0, 0, ma0)
        G1(1, 0, ma1)
        f32x4 mb0 = mload(pm + 16);
        f32x4 mb1 = mload(pm + (size_t)16 * KFR + 16);
        G1(2, 0, ma2)
        G1(3, 0, ma3)
        f32x4 mb2 = mload(pm + (size_t)32 * KFR + 16);
        f32x4 mb3 = mload(pm + (size_t)48 * KFR + 16);
        G1(0, 1, mb0)
        G1(1, 1, mb1)
        G1(2, 1, mb2)
        G1(3, 1, mb3)
        __syncthreads();   // xt ready

        // ---- phase D: est[t+1] prefetch; GEMM2 (waves 0-1); shuffle-OLA into locout ----
        {
            const float* egn = eg0 + (t + 1 < NTPB ? (t + 1) * KT : t * KT);
            er00 = *reinterpret_cast<const f32x4*>(egn + (size_t)(2 * c0) * KFR + 4 * f4);
            er01 = *reinterpret_cast<const f32x4*>(egn + (size_t)(2 * c0 + 1) * KFR + 4 * f4);
            er10 = *reinterpret_cast<const f32x4*>(egn + (size_t)(2 * c0 + 64) * KFR + 4 * f4);
            er11 = *reinterpret_cast<const f32x4*>(egn + (size_t)(2 * c0 + 65) * KFR + 4 * f4);
        }
        if (wv < 2) {
            int f = 16 * wv + l15;
            int sg = ((f >> 2) & 3) << 1;
            const unsigned int* br = xtd + f * XTW;
            const unsigned short* wb2 = wbf + NCH * BCH + l15 * NCH + 8 * lq;
            f32x4 acc2 = {0.f, 0.f, 0.f, 0.f};
#pragma unroll
            for (int ks = 0; ks < 8; ++ks) {
                bf16x8 a = *reinterpret_cast<const bf16x8*>(wb2 + 32 * ks);
                bf16x8 b = *reinterpret_cast<const bf16x8*>(br + (((4 * ks + lq) ^ sg) << 2));
                acc2 = __builtin_amdgcn_mfma_f32_16x16x32_bf16(a, b, acc2, 0, 0, 0);
            }
            // in-register overlap-add: lane (lq<2, l15) owns output quad
            // [8f+4lq, +4) = own louts + louts 8-15 of frame f-1 (lane+31)
            int src = (lane + 31) & 63;
            float p0 = __shfl(acc2[0], src, 64);
            float p1 = __shfl(acc2[1], src, 64);
            float p2 = __shfl(acc2[2], src, 64);
            float p3 = __shfl(acc2[3], src, 64);
            if (lq < 2) {
                int toff = 256 * t + 8 * f + 4 * lq;
                if (l15 == 0) {     // seam: partner lives in another wave/tile/block
                    atomicAdd(locout + toff + 0, acc2[0]);
                    atomicAdd(locout + toff + 1, acc2[1]);
                    atomicAdd(locout + toff + 2, acc2[2]);
                    atomicAdd(locout + toff + 3, acc2[3]);
                } else {            // interior: both contributions in hand
                    f32x4 s = {acc2[0] + p0, acc2[1] + p1, acc2[2] + p2, acc2[3] + p3};
                    *reinterpret_cast<f32x4*>(locout + toff) = s;
                }
            } else if (l15 == 15) { // louts 8-15 of frame 16wv+15 -> next group's seam
                int toff = 256 * t + 8 * (16 * wv + 16) + 4 * (lq - 2);
                atomicAdd(locout + toff + 0, acc2[0]);
                atomicAdd(locout + toff + 1, acc2[1]);
                atomicAdd(locout + toff + 2, acc2[2]);
                atomicAdd(locout + toff + 3, acc2[3]);
            }
        }
        // no barrier: phase A(t+1) writes estd (disjoint from xtd/locout);
        // the A-end barrier orders xt/locout reuse for all waves
    }
    __syncthreads();

    // ---- final store: plain float4 interior, atomic 8-float chunk edges ----
    {
        float* og = out + (size_t)g * TOUT + (size_t)(8 * CHUNK) * c;
        for (int s = tid; s < LOC_FLOATS / 4; s += 256) {
            f32x4 v = *reinterpret_cast<const f32x4*>(locout + 4 * s);
            if (s >= 2 && s < (LOC_FLOATS / 4 - 2)) {
                *reinterpret_cast<f32x4*>(og + 4 * s) = v;
            } else {
#pragma unroll
                for (int r = 0; r < 4; ++r) atomicAdd(og + 4 * s + r, v[r]);
            }
        }
    }
}

extern "C" void kernel_launch(void* const* d_in, const int* in_sizes, int n_in,
                              void* d_out, int out_size, void* d_ws, size_t ws_size,
                              hipStream_t stream) {
    const float* mix = (const float*)d_in[0];   // [8][256][32000]
    const float* est = (const float*)d_in[1];   // [8][128][32000]
    const float* Wm  = (const float*)d_in[2];   // [256][128]
    const float* Wb  = (const float*)d_in[3];   // [16][256]
    unsigned short* wbf = (unsigned short*)d_ws;

    hipMemsetAsync(d_out, 0, (size_t)out_size * sizeof(float), stream);
    convert_weights<<<128, 256, 0, stream>>>(Wm, Wb, wbf);
    fused_decoder<<<BATCH * NCHUNK, 256, 0, stream>>>(mix, est, wbf, (float*)d_out);
}